// Round 6
// baseline (261.941 us; speedup 1.0000x reference)
//
#include <hip/hip_runtime.h>

// DeformableConv1d: B=32, C=64, L=16384, COUT=64, K=1.
// R7: 1-barrier software pipeline. Block owns NT=8 tiles; steady interval:
//   issue stage(t+1) | mm2+store(t-1) | mm1+gather+XdWrite(t) |
//   halo-copy+stage-write(t+1) | ONE __syncthreads
// Xt and Xd both double-buffered (reads/writes hit disjoint buffers ->
// single barrier is legal). Grid 1024 = exactly 4 blocks/CU resident.
// mm2's MFMA+ds_read overlap the gather's VALU inside one interval.
// Layouts identical to R5/R6 (verified): Xt f16 [row][c] 72 rows stride 36
// words XOR-swizzled; Xd f16 [l][c] 64 rows same swizzle. Halo rows of
// tile t+1 copied LDS->LDS from tile t (swizzle-compatible, 64 = 0 mod 32).
// frac from p = l + offset in fp32, matching reference exactly.

#define BDIM 256
#define BB   32
#define CC   64
#define LL   16384
#define TL   64                  // l per tile
#define HH   4                   // gather halo
#define ROWS (TL + 2*HH)         // 72 staged rows
#define RSW  36                  // row stride (words, 144 B)
#define RSH  72                  // row stride (halfwords)
#define NT   8                   // tiles per block
#define XTW  (ROWS * RSW)        // 2592 words per Xt buffer
#define XDW  (TL * RSW)          // 2304 words per Xd buffer

typedef __fp16 half_t;
typedef __attribute__((ext_vector_type(2))) __fp16 h2;
typedef __attribute__((ext_vector_type(8))) __fp16 h8;
typedef __attribute__((ext_vector_type(4))) float f4;

union H2U { h2 h; unsigned u; };
union H8U { unsigned u[4]; h8 v; };

static __device__ __forceinline__ unsigned pk(float a, float b) {
    H2U r; r.h = __builtin_amdgcn_cvt_pkrtz(a, b); return r.u;
}

static __device__ __forceinline__ void load_a_split(const float* __restrict__ wp,
                                                    int row, int ks, int q,
                                                    h8* ahi, h8* alo) {
    const float* base = wp + row * 64 + ks * 32 + q * 8;
    float4 w0 = *(const float4*)base;
    float4 w1 = *(const float4*)(base + 4);
    float v[8] = {w0.x, w0.y, w0.z, w0.w, w1.x, w1.y, w1.z, w1.w};
    H8U h, l;
    #pragma unroll
    for (int p = 0; p < 4; ++p) {
        H2U hh; hh.h = __builtin_amdgcn_cvt_pkrtz(v[2*p], v[2*p+1]);
        h.u[p] = hh.u;
        l.u[p] = pk(v[2*p] - (float)hh.h[0], v[2*p+1] - (float)hh.h[1]);
    }
    *ahi = h.v; *alo = l.v;
}

static __device__ __forceinline__ h8 load_a_f16(const float* __restrict__ wp,
                                                int row, int ks, int q) {
    const float* base = wp + row * 64 + ks * 32 + q * 8;
    float4 w0 = *(const float4*)base;
    float4 w1 = *(const float4*)(base + 4);
    float v[8] = {w0.x, w0.y, w0.z, w0.w, w1.x, w1.y, w1.z, w1.w};
    H8U r;
    #pragma unroll
    for (int p = 0; p < 4; ++p) r.u[p] = pk(v[2*p], v[2*p+1]);
    return r.v;
}

// write one 4ch x 4l staged tile (channels 4cb.., rows rowb..rowb+3)
static __device__ __forceinline__ void stage_write4(unsigned* dst, int cb, int rowb,
                                                    const float4& v0, const float4& v1,
                                                    const float4& v2, const float4& v3) {
    float a0[4] = {v0.x, v0.y, v0.z, v0.w};
    float a1[4] = {v1.x, v1.y, v1.z, v1.w};
    float a2[4] = {v2.x, v2.y, v2.z, v2.w};
    float a3[4] = {v3.x, v3.y, v3.z, v3.w};
    int wbase = rowb * RSW + (((cb >> 1) ^ ((rowb >> 2) & 7)) << 2) + 2 * (cb & 1);
    #pragma unroll
    for (int rl = 0; rl < 4; ++rl) {
        uint2 hw;
        hw.x = pk(a0[rl], a1[rl]);
        hw.y = pk(a2[rl], a3[rl]);
        *(uint2*)&dst[wbase + rl * RSW] = hw;
    }
}

// mm2: out(tile at lg0) = Wr * Xd + br, then store
static __device__ __forceinline__ void mm2_store(const unsigned* __restrict__ Xd,
                                                 const h8* a2f, const float4& br,
                                                 float* __restrict__ op, int lg0,
                                                 int wv, int q, int n) {
    f4 acc[4];
    #pragma unroll
    for (int nt = 0; nt < 4; ++nt) acc[nt] = (f4){br.x, br.y, br.z, br.w};
    #pragma unroll
    for (int nt = 0; nt < 4; ++nt) {
        const int row = 16 * nt + n;
        const int sb  = (row >> 2) & 7;
        #pragma unroll
        for (int ks = 0; ks < 2; ++ks) {
            int blk = (4 * ks + q) ^ sb;
            h8 bv = *(const h8*)&Xd[row * RSW + (blk << 2)];
            acc[nt] = __builtin_amdgcn_mfma_f32_16x16x32_f16(a2f[ks], bv, acc[nt], 0, 0, 0);
        }
    }
    #pragma unroll
    for (int nt = 0; nt < 4; ++nt) {
        #pragma unroll
        for (int reg = 0; reg < 4; ++reg) {
            op[(size_t)(16 * wv + 4 * q + reg) * LL + lg0 + 16 * nt + n] = acc[nt][reg];
        }
    }
}

__global__ __launch_bounds__(BDIM)
void deform_conv1d_r7(const float* __restrict__ x,
                      const float* __restrict__ offw,
                      const float* __restrict__ offb,
                      const float* __restrict__ regw,
                      const float* __restrict__ regb,
                      float* __restrict__ out) {
    __shared__ __align__(16) unsigned smem[2 * XTW + 2 * XDW];   // 39168 B
    unsigned* XT = smem;
    unsigned* XD = smem + 2 * XTW;

    const int tid = threadIdx.x;
    const int bx  = blockIdx.x;           // 0..31
    const int b   = blockIdx.y;
    const size_t xb = (size_t)b * CC * LL;
    float* op = out + (size_t)b * CC * LL;

    const int wv   = tid >> 6;
    const int lane = tid & 63;
    const int q    = lane >> 4;
    const int n    = lane & 15;
    const int scb  = tid >> 4;            // stage channel-block 0..15
    const int slb  = tid & 15;            // stage l-block 0..15 (fast: coalesce)

    // ---------------- prologue: stage tile0 into XT[0] ----------------------
    {
        const int lg0 = (NT * bx) * TL;
        unsigned* dst = XT;
        half_t*  dsth = (half_t*)XT;
        if (bx == 0) {                                // clamped slow path
            for (int i = tid; i < ROWS * CC; i += BDIM) {
                int r = i >> 6, c = i & 63;
                int g = min(max(lg0 - HH + r, 0), LL - 1);
                float v = x[xb + (size_t)c * LL + g];
                int blk = (c >> 3) ^ ((r >> 2) & 7);
                dsth[r * RSH + (blk << 3) + (c & 7)] = (half_t)v;
            }
        } else {
            const float* pp = x + xb + (size_t)(4 * scb) * LL + (lg0 + 4 + 4 * slb);
            float4 v0 = *(const float4*)pp;
            float4 v1 = *(const float4*)(pp + LL);
            float4 v2 = *(const float4*)(pp + 2 * LL);
            float4 v3 = *(const float4*)(pp + 3 * LL);
            stage_write4(dst, scb, 8 + 4 * slb, v0, v1, v2, v3);
            if (tid < 32) {                           // rows 0..7
                int lb2 = tid & 1, cb2 = tid >> 1;
                const float* p2 = x + xb + (size_t)(4 * cb2) * LL + (lg0 - 4 + 4 * lb2);
                float4 u0 = *(const float4*)p2;
                float4 u1 = *(const float4*)(p2 + LL);
                float4 u2 = *(const float4*)(p2 + 2 * LL);
                float4 u3 = *(const float4*)(p2 + 3 * LL);
                stage_write4(dst, cb2, 4 * lb2, u0, u1, u2, u3);
            }
        }
    }

    // ---------------- weights/biases: once per block ------------------------
    h8 ahi[2], alo[2], a2f[2];
    load_a_split(offw, 16 * wv + n, 0, q, &ahi[0], &alo[0]);
    load_a_split(offw, 16 * wv + n, 1, q, &ahi[1], &alo[1]);
    a2f[0] = load_a_f16(regw, 16 * wv + n, 0, q);
    a2f[1] = load_a_f16(regw, 16 * wv + n, 1, q);
    float4 bo = *(const float4*)(offb + 16 * wv + 4 * q);
    float4 br = *(const float4*)(regb + 16 * wv + 4 * q);
    __syncthreads();

    for (int tt = 0; tt < NT; ++tt) {
        const int lg0 = (NT * bx + tt) * TL;
        unsigned* Xc  = XT + (tt & 1) * XTW;
        unsigned* Xn  = XT + ((tt & 1) ^ 1) * XTW;
        half_t*   Xch = (half_t*)Xc;
        unsigned* XdC = XD + (tt & 1) * XDW;
        unsigned* XdP = XD + ((tt & 1) ^ 1) * XDW;
        const bool has_next  = (tt < NT - 1);
        const bool next_fast = has_next && !(bx == 31 && tt == NT - 2);

        // ---- (1) issue next-tile stage loads (rows 8..71 of tile tt+1) ----
        float4 s0, s1, s2, s3;
        if (next_fast) {
            const float* pp = x + xb + (size_t)(4 * scb) * LL + (lg0 + TL + 4 + 4 * slb);
            s0 = *(const float4*)pp;
            s1 = *(const float4*)(pp + LL);
            s2 = *(const float4*)(pp + 2 * LL);
            s3 = *(const float4*)(pp + 3 * LL);
        }

        // ---- (2) mm2 + store for tile tt-1 (overlaps mm1/gather below) ----
        if (tt > 0) mm2_store(XdP, a2f, br, op, lg0 - TL, wv, q, n);

        // ---- (3) mm1: offsets = Wo*x + bo (2-pass split weight) -----------
        f4 acc[4];
        #pragma unroll
        for (int nt = 0; nt < 4; ++nt) acc[nt] = (f4){bo.x, bo.y, bo.z, bo.w};
        #pragma unroll
        for (int nt = 0; nt < 4; ++nt) {
            const int r  = 16 * nt + n + HH;
            const int rb = r * RSW;
            const int sb = (r >> 2) & 7;
            #pragma unroll
            for (int ks = 0; ks < 2; ++ks) {
                int blk = (4 * ks + q) ^ sb;
                h8 bv = *(const h8*)&Xc[rb + (blk << 2)];
                acc[nt] = __builtin_amdgcn_mfma_f32_16x16x32_f16(ahi[ks], bv, acc[nt], 0, 0, 0);
                acc[nt] = __builtin_amdgcn_mfma_f32_16x16x32_f16(alo[ks], bv, acc[nt], 0, 0, 0);
            }
        }

        // ---- (4) gather + lerp (acc := x_deform), ref-exact frac ----------
        #pragma unroll
        for (int nt = 0; nt < 4; ++nt) {
            const int l = lg0 + 16 * nt + n;
            #pragma unroll
            for (int reg = 0; reg < 4; ++reg) {
                const int c = 16 * wv + 4 * q + reg;
                float o  = acc[nt][reg];
                float p  = (float)l + o;
                p = __builtin_amdgcn_fmed3f(p, 0.0f, (float)(LL - 1));
                float of = floorf(p);
                float fr = p - of;
                int idx  = (int)of;
                int u    = idx - lg0 + HH;
                float x0, x1;
                if ((unsigned)u <= (unsigned)(ROWS - 2)) {
                    int b0 = (c >> 3) ^ ((u >> 2) & 7);
                    int b1 = (c >> 3) ^ (((u + 1) >> 2) & 7);
                    x0 = (float)Xch[u * RSH + (b0 << 3) + (c & 7)];
                    x1 = (float)Xch[(u + 1) * RSH + (b1 << 3) + (c & 7)];
                } else {                               // |off|>4: ~never
                    const float* xr = x + xb + (size_t)c * LL;
                    x0 = xr[idx];
                    x1 = xr[idx + (fr > 0.0f ? 1 : 0)];
                }
                acc[nt][reg] = x0 + fr * (x1 - x0);
            }
        }

        // ---- (5) x_deform -> XdC, block-XOR swizzled ----------------------
        #pragma unroll
        for (int nt = 0; nt < 4; ++nt) {
            const int row = 16 * nt + n;
            const int sb  = (row >> 2) & 7;
            const int bw  = (2 * wv + (q >> 1)) ^ sb;
            uint2 pw;
            pw.x = pk(acc[nt][0], acc[nt][1]);
            pw.y = pk(acc[nt][2], acc[nt][3]);
            *(uint2*)&XdC[row * RSW + (bw << 2) + 2 * (q & 1)] = pw;
        }

        // ---- (6) halo copy + staged write into next Xt buffer -------------
        if (has_next) {
            if (tid < 144) {   // rows 0..7 of t+1 == rows 64..71 of t
                int j  = tid / 18;
                int k2 = (tid - 18 * j) * 2;
                *(uint2*)&Xn[j * RSW + k2] = *(const uint2*)&Xc[(64 + j) * RSW + k2];
            }
            if (next_fast) {
                stage_write4(Xn, scb, 8 + 4 * slb, s0, s1, s2, s3);
            } else {                                   // tile 255: clamped
                half_t* Xnh = (half_t*)Xn;
                for (int i = tid; i < TL * CC; i += BDIM) {
                    int r = 8 + (i >> 6), c = i & 63;
                    int g = min(lg0 + TL - HH + r, LL - 1);
                    float v = x[xb + (size_t)c * LL + g];
                    int blk = (c >> 3) ^ ((r >> 2) & 7);
                    Xnh[r * RSH + (blk << 3) + (c & 7)] = (half_t)v;
                }
            }
        }
        __syncthreads();
    }

    // ---------------- epilogue: mm2 + store for last tile -------------------
    mm2_store(XD + ((NT - 1) & 1) * XDW, a2f, br, op,
              (NT * bx + NT - 1) * TL, wv, q, n);
}

extern "C" void kernel_launch(void* const* d_in, const int* in_sizes, int n_in,
                              void* d_out, int out_size, void* d_ws, size_t ws_size,
                              hipStream_t stream) {
    const float* x    = (const float*)d_in[0];   // [32,64,16384]
    const float* offw = (const float*)d_in[1];   // [64,64,1]
    const float* offb = (const float*)d_in[2];   // [64]
    const float* regw = (const float*)d_in[3];   // [64,64,1]
    const float* regb = (const float*)d_in[4];   // [64]
    float* out = (float*)d_out;                  // [32,64,16384]

    dim3 grid(LL / TL / NT, BB);
    deform_conv1d_r7<<<grid, dim3(BDIM), 0, stream>>>(x, offw, offb, regw, regb, out);
}